// Round 2
// baseline (1501.654 us; speedup 1.0000x reference)
//
#include <hip/hip_runtime.h>
#include <hip/hip_bf16.h>
#include <math.h>

#define D_  1024
#define B_  32
#define T_  2048
#define L_  8
#define P_  720
#define E_  16
#define BP_ (B_*P_)   /* 23040 */

// ---- workspace layout (float offsets) ----
#define OFF_STEPB   ((size_t)0)        // [720][1024]
#define OFF_CKWT    ((size_t)737280)   // ctx_k_w^T  [1024][1024]
#define OFF_SQWT    ((size_t)1785856)  // step_q_w^T [1024][1024]
#define OFF_SB1T    ((size_t)2834432)  // [1024][720]
#define OFF_K2PT    ((size_t)3571712)  // [1024][256]
#define OFF_LOGIT   ((size_t)3833856)  // [B*P][16]
#define OFF_DENR    ((size_t)4202496)  // [256]
// ---- memset (atomic-accumulate) region starts here ----
#define OFF_Q1      ((size_t)4202752)  // [8][1024]
#define OFF_Q1P     ((size_t)4210944)  // [8][1024]
#define OFF_NUM     ((size_t)4219136)  // [B*8][1024]
#define OFF_DENS    ((size_t)4481280)  // [256]
#define OFF_TMP1    ((size_t)4481536)  // [256][1024]
#define OFF_LATC    ((size_t)4743680)
#define OFF_K2      ((size_t)5005824)
#define OFF_V2      ((size_t)5267968)
#define OFF_K2P     ((size_t)5530112)
#define OFF_V2A     ((size_t)5792256)
#define OFF_V2P     ((size_t)6054400)
#define OFF_S2      ((size_t)6316544)  // [720][256]
#define OFF_SB1     ((size_t)6500864)  // [720][1024]
// ---- memset region ends here ----
#define WS_FLOATS   ((size_t)7238144)  // ~29 MB

__device__ __forceinline__ float gelu_exact(float x){
    return 0.5f * x * (1.0f + erff(x * 0.70710678118654752f));
}

// step_base[p][d] = query_pos[p][d] + pred_len_table[720][d]
__global__ void k_stepb(const float* __restrict__ qpos, const float* __restrict__ plt,
                        float* __restrict__ stepb){
    int p = blockIdx.x;
    int d = threadIdx.x * 4;
    float4 a = *(const float4*)(qpos + (size_t)p*D_ + d);
    float4 b = *(const float4*)(plt  + (size_t)P_*D_ + d);
    a.x += b.x; a.y += b.y; a.z += b.z; a.w += b.w;
    *(float4*)(stepb + (size_t)p*D_ + d) = a;
}

// generic guarded transpose: dst[C][R] = src[R][C]^T, 32x32 tiles
__global__ void k_tr(const float* __restrict__ src, float* __restrict__ dst, int R, int C){
    __shared__ float tile[32][33];
    int tx = threadIdx.x & 31, ty = threadIdx.x >> 5;   // ty in [0,8)
    int c0 = blockIdx.x * 32, r0 = blockIdx.y * 32;
    #pragma unroll
    for (int r = 0; r < 4; r++){
        int rr = r0 + ty + 8*r;
        if (rr < R && c0 + tx < C) tile[ty + 8*r][tx] = src[(size_t)rr*C + c0 + tx];
    }
    __syncthreads();
    #pragma unroll
    for (int r = 0; r < 4; r++){
        int cc = c0 + ty + 8*r;
        if (cc < C && r0 + tx < R) dst[(size_t)cc*R + r0 + tx] = tile[tx][ty + 8*r];
    }
}

// C[M,N] (+)= rowscale * A[M,1024(chunk)] @ B[1024(chunk),N]; split-K via gridDim.z, atomic epilogue.
__global__ void k_gemm(const float* __restrict__ A, const float* __restrict__ B,
                       float* __restrict__ C, int M, int N, const float* __restrict__ rowscale){
    int n  = blockIdx.y * 256 + threadIdx.x;
    int kc = D_ / gridDim.z;
    int k0 = blockIdx.z * kc;
    int mb = blockIdx.x * 16;
    float acc[16];
    #pragma unroll
    for (int m = 0; m < 16; m++) acc[m] = 0.f;
    for (int k = k0; k < k0 + kc; k += 4){
        float b0 = B[(size_t)(k+0)*N + n];
        float b1 = B[(size_t)(k+1)*N + n];
        float b2 = B[(size_t)(k+2)*N + n];
        float b3 = B[(size_t)(k+3)*N + n];
        #pragma unroll
        for (int m = 0; m < 16; m++){
            int row = mb + m; if (row > M - 1) row = M - 1;   // uniform clamp
            const float4 av = *(const float4*)(A + (size_t)row*D_ + k);
            acc[m] += av.x*b0 + av.y*b1 + av.z*b2 + av.w*b3;
        }
    }
    #pragma unroll
    for (int m = 0; m < 16; m++){
        int row = mb + m;
        if (row < M){
            float v = acc[m];
            if (rowscale) v *= rowscale[row];
            atomicAdd(C + (size_t)row*N + n, v);
        }
    }
}

// Fused stage-1 attention: one HBM pass over ctx.
// block = (b, chunk of 64 t), 256 threads; wave w owns d-quarter [w*256, w*256+256).
__global__ void __launch_bounds__(256, 4)
k_attn1(const float* __restrict__ ctx, const float* __restrict__ q1p,
        float* __restrict__ num, float* __restrict__ densum){
    __shared__ float part[4][8][8];   // [wave][row][l]
    __shared__ float es[8][8];        // expS for current sub-chunk
    int b   = blockIdx.x;
    int tc  = blockIdx.y;
    int tid = threadIdx.x;
    int w    = tid >> 6;
    int lane = tid & 63;
    // q1p fragment for this lane's 4 d-values, all 8 latents (32 VGPRs)
    float4 q[8];
    #pragma unroll
    for (int l = 0; l < 8; l++)
        q[l] = *(const float4*)(q1p + (size_t)l*D_ + w*256 + lane*4);
    float4 acc2[8];
    #pragma unroll
    for (int l = 0; l < 8; l++) acc2[l] = make_float4(0,0,0,0);
    float dsum = 0.f;
    const float* cbase = ctx + ((size_t)b * T_ + (size_t)tc * 64) * D_;
    for (int sc = 0; sc < 8; sc++){
        float4 c8[8];
        // phase 1: partial dots for 8 rows
        #pragma unroll
        for (int r = 0; r < 8; r++){
            int t = sc*8 + r;
            c8[r] = *(const float4*)(cbase + (size_t)t*D_ + w*256 + lane*4);
            float acc[8];
            #pragma unroll
            for (int l = 0; l < 8; l++)
                acc[l] = c8[r].x*q[l].x + c8[r].y*q[l].y + c8[r].z*q[l].z + c8[r].w*q[l].w;
            #pragma unroll
            for (int m = 1; m < 64; m <<= 1){
                #pragma unroll
                for (int l = 0; l < 8; l++) acc[l] += __shfl_xor(acc[l], m, 64);
            }
            if (lane == 0){
                *(float4*)&part[w][r][0] = make_float4(acc[0],acc[1],acc[2],acc[3]);
                *(float4*)&part[w][r][4] = make_float4(acc[4],acc[5],acc[6],acc[7]);
            }
        }
        __syncthreads();
        // combine quarters + exp
        if (tid < 64){
            int r = tid >> 3, l = tid & 7;
            float s = part[0][r][l] + part[1][r][l] + part[2][r][l] + part[3][r][l];
            float e = __expf(s * 0.03125f);
            es[r][l] = e;
            dsum += e;
        }
        __syncthreads();
        // phase 2: weighted accumulate (ctx from regs)
        #pragma unroll
        for (int r = 0; r < 8; r++){
            float4 e0 = *(const float4*)&es[r][0];
            float4 e1 = *(const float4*)&es[r][4];
            float4 c = c8[r];
            acc2[0].x += e0.x*c.x; acc2[0].y += e0.x*c.y; acc2[0].z += e0.x*c.z; acc2[0].w += e0.x*c.w;
            acc2[1].x += e0.y*c.x; acc2[1].y += e0.y*c.y; acc2[1].z += e0.y*c.z; acc2[1].w += e0.y*c.w;
            acc2[2].x += e0.z*c.x; acc2[2].y += e0.z*c.y; acc2[2].z += e0.z*c.z; acc2[2].w += e0.z*c.w;
            acc2[3].x += e0.w*c.x; acc2[3].y += e0.w*c.y; acc2[3].z += e0.w*c.z; acc2[3].w += e0.w*c.w;
            acc2[4].x += e1.x*c.x; acc2[4].y += e1.x*c.y; acc2[4].z += e1.x*c.z; acc2[4].w += e1.x*c.w;
            acc2[5].x += e1.y*c.x; acc2[5].y += e1.y*c.y; acc2[5].z += e1.y*c.z; acc2[5].w += e1.y*c.w;
            acc2[6].x += e1.z*c.x; acc2[6].y += e1.z*c.y; acc2[6].z += e1.z*c.z; acc2[6].w += e1.z*c.w;
            acc2[7].x += e1.w*c.x; acc2[7].y += e1.w*c.y; acc2[7].z += e1.w*c.z; acc2[7].w += e1.w*c.w;
        }
        __syncthreads();
    }
    int d = tid * 4;
    #pragma unroll
    for (int l = 0; l < 8; l++){
        float* np_ = num + ((size_t)(b*8 + l))*D_ + d;
        atomicAdd(np_+0, acc2[l].x); atomicAdd(np_+1, acc2[l].y);
        atomicAdd(np_+2, acc2[l].z); atomicAdd(np_+3, acc2[l].w);
    }
    if (tid < 64) atomicAdd(densum + b*8 + (tid & 7), dsum);
}

__global__ void k_dinv(const float* __restrict__ densum, float* __restrict__ denr){
    int i = threadIdx.x;
    denr[i] = 1.0f / densum[i];
}

// fused: softmax(S2) -> pre -> gelu -> logits. block=(b, ptile of 64), wave-quartet over d.
__global__ void k_f2(const float* __restrict__ SB1T, const float* __restrict__ v2p,
                     const float* __restrict__ S2, const float* __restrict__ b1,
                     const float* __restrict__ w2, const float* __restrict__ b2,
                     float* __restrict__ logits){
    __shared__ float red[4][64][16];
    int b   = blockIdx.x;
    int py  = blockIdx.y;
    int tid = threadIdx.x;
    int pl = tid & 63, ds = tid >> 6;
    int p  = py*64 + pl;
    int pc = (p < P_) ? p : (P_ - 1);
    // softmax over L=8 from S2[pc][b*8 + l]
    float a[8];
    {
        float4 s0 = *(const float4*)(S2 + (size_t)pc*256 + b*8);
        float4 s1 = *(const float4*)(S2 + (size_t)pc*256 + b*8 + 4);
        a[0]=s0.x*0.03125f; a[1]=s0.y*0.03125f; a[2]=s0.z*0.03125f; a[3]=s0.w*0.03125f;
        a[4]=s1.x*0.03125f; a[5]=s1.y*0.03125f; a[6]=s1.z*0.03125f; a[7]=s1.w*0.03125f;
        float m = a[0];
        #pragma unroll
        for (int l = 1; l < 8; l++) m = fmaxf(m, a[l]);
        float sum = 0.f;
        #pragma unroll
        for (int l = 0; l < 8; l++){ a[l] = __expf(a[l] - m); sum += a[l]; }
        float inv = 1.0f / sum;
        #pragma unroll
        for (int l = 0; l < 8; l++) a[l] *= inv;
    }
    float acc[16];
    #pragma unroll
    for (int e = 0; e < 16; e++) acc[e] = 0.f;
    const float* vb = v2p + (size_t)b*8*D_;
    int d0 = ds * 256;
    for (int dd = 0; dd < 256; dd += 4){
        int d = d0 + dd;
        float4 bb = *(const float4*)(b1 + d);                 // uniform
        float pre[4];
        pre[0] = SB1T[(size_t)(d+0)*P_ + pc] + bb.x;
        pre[1] = SB1T[(size_t)(d+1)*P_ + pc] + bb.y;
        pre[2] = SB1T[(size_t)(d+2)*P_ + pc] + bb.z;
        pre[3] = SB1T[(size_t)(d+3)*P_ + pc] + bb.w;
        #pragma unroll
        for (int l = 0; l < 8; l++){
            float4 vv = *(const float4*)(vb + (size_t)l*D_ + d);  // uniform
            pre[0] += a[l]*vv.x; pre[1] += a[l]*vv.y;
            pre[2] += a[l]*vv.z; pre[3] += a[l]*vv.w;
        }
        #pragma unroll
        for (int j = 0; j < 4; j++){
            float h = gelu_exact(pre[j]);
            const float* w2r = w2 + (size_t)(d + j) * E_;     // uniform
            #pragma unroll
            for (int e = 0; e < 16; e++) acc[e] += h * w2r[e];
        }
    }
    float* rp = &red[ds][pl][0];
    #pragma unroll
    for (int e = 0; e < 16; e += 4)
        *(float4*)(rp + e) = make_float4(acc[e], acc[e+1], acc[e+2], acc[e+3]);
    __syncthreads();
    for (int idx = tid; idx < 1024; idx += 256){
        int pp = idx >> 4, e = idx & 15;
        int gp = py*64 + pp;
        if (gp < P_){
            float v = red[0][pp][e] + red[1][pp][e] + red[2][pp][e] + red[3][pp][e] + b2[e];
            logits[((size_t)b*P_ + gp)*16 + e] = v;
        }
    }
}

// top-2 + masked softmax + expert combine
__global__ void k_f3(const float* __restrict__ logits, const float* __restrict__ qe,
                     float* __restrict__ out){
    int p = blockIdx.x, b = blockIdx.y;
    size_t bp = (size_t)b * P_ + p;
    float lg[16];
    #pragma unroll
    for (int e = 0; e < 16; e += 4){
        float4 v = *(const float4*)(logits + bp*16 + e);
        lg[e]=v.x; lg[e+1]=v.y; lg[e+2]=v.z; lg[e+3]=v.w;
    }
    int e1 = 0; float l1 = lg[0];
    #pragma unroll
    for (int e = 1; e < 16; e++) if (lg[e] > l1){ l1 = lg[e]; e1 = e; }
    int e2 = 0; float l2 = -1e30f;
    #pragma unroll
    for (int e = 0; e < 16; e++) if (e != e1 && lg[e] > l2){ l2 = lg[e]; e2 = e; }
    float qr = __expf(l2 - l1);
    float w1 = 1.0f / (1.0f + qr);
    float w2 = qr / (1.0f + qr);
    int d = threadIdx.x * 4;
    float4 x1 = *(const float4*)(qe + ((size_t)e1 * P_ + p)*D_ + d);
    float4 x2 = *(const float4*)(qe + ((size_t)e2 * P_ + p)*D_ + d);
    float4 o;
    o.x = w1*x1.x + w2*x2.x; o.y = w1*x1.y + w2*x2.y;
    o.z = w1*x1.z + w2*x2.z; o.w = w1*x1.w + w2*x2.w;
    *(float4*)(out + bp*D_ + d) = o;
}

extern "C" void kernel_launch(void* const* d_in, const int* in_sizes, int n_in,
                              void* d_out, int out_size, void* d_ws, size_t ws_size,
                              hipStream_t stream) {
    (void)in_sizes; (void)n_in; (void)out_size; (void)ws_size;
    const float* ctx  = (const float*)d_in[0];
    const float* qexp = (const float*)d_in[1];
    const float* qpos = (const float*)d_in[2];
    const float* plt  = (const float*)d_in[3];
    const float* lats = (const float*)d_in[4];
    const float* w_lq = (const float*)d_in[5];
    const float* w_ck = (const float*)d_in[6];
    const float* w_cv = (const float*)d_in[7];
    const float* w_lo = (const float*)d_in[8];
    const float* w_sq = (const float*)d_in[9];
    const float* w_lk = (const float*)d_in[10];
    const float* w_lv = (const float*)d_in[11];
    const float* w_so = (const float*)d_in[12];
    const float* w_g1 = (const float*)d_in[13];
    const float* b_g1 = (const float*)d_in[14];
    const float* w_g2 = (const float*)d_in[15];
    const float* b_g2 = (const float*)d_in[16];
    float* out = (float*)d_out;
    float* ws  = (float*)d_ws;

    float* stepb  = ws + OFF_STEPB;
    float* ckwT   = ws + OFF_CKWT;
    float* sqwT   = ws + OFF_SQWT;
    float* SB1T   = ws + OFF_SB1T;
    float* k2pT   = ws + OFF_K2PT;
    float* logits = ws + OFF_LOGIT;
    float* denr   = ws + OFF_DENR;
    float* q1     = ws + OFF_Q1;
    float* q1p    = ws + OFF_Q1P;
    float* num    = ws + OFF_NUM;
    float* densum = ws + OFF_DENS;
    float* tmp1   = ws + OFF_TMP1;
    float* latctx = ws + OFF_LATC;
    float* k2     = ws + OFF_K2;
    float* v2     = ws + OFF_V2;
    float* k2p    = ws + OFF_K2P;
    float* v2a    = ws + OFF_V2A;
    float* v2p    = ws + OFF_V2P;
    float* S2     = ws + OFF_S2;
    float* SB1    = ws + OFF_SB1;

    hipMemsetAsync(q1, 0, (WS_FLOATS - OFF_Q1) * sizeof(float), stream);

    k_stepb<<<dim3(P_), dim3(256), 0, stream>>>(qpos, plt, stepb);
    k_tr<<<dim3(32,32), dim3(256), 0, stream>>>(w_ck, ckwT, 1024, 1024);
    k_tr<<<dim3(32,32), dim3(256), 0, stream>>>(w_sq, sqwT, 1024, 1024);

    k_gemm<<<dim3(1,4,8),  dim3(256), 0, stream>>>(lats, w_lq, q1,  8,   1024, nullptr);
    k_gemm<<<dim3(1,4,8),  dim3(256), 0, stream>>>(q1,   ckwT, q1p, 8,   1024, nullptr);

    k_attn1<<<dim3(B_, 32), dim3(256), 0, stream>>>(ctx, q1p, num, densum);
    k_dinv<<<dim3(1), dim3(256), 0, stream>>>(densum, denr);

    k_gemm<<<dim3(16,4,8), dim3(256), 0, stream>>>(num,    w_cv, tmp1,   256, 1024, denr);
    k_gemm<<<dim3(16,4,8), dim3(256), 0, stream>>>(tmp1,   w_lo, latctx, 256, 1024, nullptr);
    k_gemm<<<dim3(16,4,8), dim3(256), 0, stream>>>(latctx, w_lk, k2,     256, 1024, nullptr);
    k_gemm<<<dim3(16,4,8), dim3(256), 0, stream>>>(latctx, w_lv, v2,     256, 1024, nullptr);
    k_gemm<<<dim3(16,4,8), dim3(256), 0, stream>>>(k2,     sqwT, k2p,    256, 1024, nullptr);
    k_gemm<<<dim3(16,4,8), dim3(256), 0, stream>>>(v2,     w_so, v2a,    256, 1024, nullptr);
    k_gemm<<<dim3(16,4,8), dim3(256), 0, stream>>>(v2a, w_g1 + (size_t)D_*D_, v2p, 256, 1024, nullptr);

    k_gemm<<<dim3(45,4,8), dim3(256), 0, stream>>>(stepb, w_g1, SB1, P_, 1024, nullptr);

    k_tr<<<dim3(32,23), dim3(256), 0, stream>>>(SB1, SB1T, P_, 1024);
    k_tr<<<dim3(32,8),  dim3(256), 0, stream>>>(k2p, k2pT, 256, 1024);

    k_gemm<<<dim3(45,1,8), dim3(256), 0, stream>>>(stepb, k2pT, S2, P_, 256, nullptr);

    k_f2<<<dim3(B_, 12), dim3(256), 0, stream>>>(SB1T, v2p, S2, b_g1, w_g2, b_g2, logits);
    k_f3<<<dim3(P_, B_), dim3(256), 0, stream>>>(logits, qexp, out);
}